// Round 6
// baseline (451.881 us; speedup 1.0000x reference)
//
#include <hip/hip_runtime.h>
#include <hip/hip_bf16.h>
#include <math.h>

typedef __attribute__((ext_vector_type(8))) short short8;
typedef __attribute__((ext_vector_type(4))) float floatx4;

#define T_LEN 1024
#define D_H 512
#define ND 2048
#define KEXP 15
#define DFFN 828
#define DFFN_P 896
#define BT_TOT 2048
#define PHI_ROWS 360
#define PHI_ROWS_P 384
#define PAIR_CAP 10240  // sum of per-expert 128-rounded counts <= 8192+15*127

// per-expert packed bf16 weight layout (elements)
#define WD_OFF   0
#define WU_OFF   262144
#define GATE_OFF 524288
#define UP_OFF   983040
#define DOWN_OFF 1441792
#define EXPW     1900544

#define BK 32

__device__ __forceinline__ float sigmoidf_(float x) { return 1.f / (1.f + expf(-x)); }
__device__ __forceinline__ unsigned short bf16b_(float x) {
    __hip_bfloat16 h = __float2bfloat16(x);
    return *reinterpret_cast<unsigned short*>(&h);
}

// async global->LDS, 16B per lane; LDS dest = wave-uniform base + lane*16
__device__ __forceinline__ void gload16(const __hip_bfloat16* g, unsigned short* l) {
    __builtin_amdgcn_global_load_lds(
        (const __attribute__((address_space(1))) void*)(uintptr_t)g,
        (__attribute__((address_space(3))) void*)(unsigned int)(uintptr_t)l,
        16, 0, 0);
}

// ---------------- fused rmsnorm + router + list build ----------------
__global__ __launch_bounds__(256) void prep_kernel(
    const float* __restrict__ stream, const float* __restrict__ rw,
    __hip_bfloat16* __restrict__ xn, float* __restrict__ gate_out,
    float* __restrict__ lp_out, int* __restrict__ cnt,
    int* __restrict__ list, int* __restrict__ pos)
{
    int bt = blockIdx.x; int b = bt >> 10; int t = bt & 1023;
    int tid = threadIdx.x;
    int wave = tid >> 6, lane = tid & 63;
    float v[8]; float ss = 0.f;
#pragma unroll
    for (int w = 0; w < 8; ++w) {
        int j = tid + w * 256;
        int n = j >> 9, d = j & 511;
        float x = stream[(((size_t)b * 4 + n) * T_LEN + t) * D_H + d];
        v[w] = x; ss += x * x;
    }
    // mean over n: thread tid holds all 4 n for d=tid (w even) and d=tid+256 (w odd)
    float m0 = 0.25f * (v[0] + v[2] + v[4] + v[6]);
    float m1 = 0.25f * (v[1] + v[3] + v[5] + v[7]);
    __shared__ float redE[4][16];
    __shared__ float logit_s[16];
    for (int e = 0; e < 16; ++e) {
        float p = m0 * rw[e * D_H + tid] + m1 * rw[e * D_H + tid + 256];
#pragma unroll
        for (int off = 32; off; off >>= 1) p += __shfl_xor(p, off, 64);
        if (lane == 0) redE[wave][e] = p;
    }
#pragma unroll
    for (int off = 32; off; off >>= 1) ss += __shfl_down(ss, off, 64);
    __shared__ float redS[4];
    if (lane == 0) redS[wave] = ss;
    __syncthreads();
    if (tid < 16) logit_s[tid] = redE[0][tid] + redE[1][tid] + redE[2][tid] + redE[3][tid];
    __syncthreads();
    if (tid == 0) {
        float pr[16];
        float mx = logit_s[0];
        for (int e = 1; e < 16; ++e) mx = fmaxf(mx, logit_s[e]);
        float sum = 0.f;
        for (int e = 0; e < 16; ++e) { pr[e] = expf(logit_s[e] - mx); sum += pr[e]; }
        float inv = 1.f / sum;
        for (int e = 0; e < 16; ++e) pr[e] *= inv;
        float gate[16]; bool taken[16];
        for (int e = 0; e < 16; ++e) { gate[e] = 0.f; taken[e] = false; }
        float prefix = 0.f;
        for (int rank = 0; rank < 4; ++rank) {
            int best = -1; float bp = -1.f;
            for (int e = 0; e < 16; ++e)
                if (!taken[e] && pr[e] > bp) { bp = pr[e]; best = e; }
            taken[best] = true;
            bool sel = (rank == 0) || (prefix < 0.8f);
            if (sel) gate[best] = bp;
            prefix += bp;
            if (!sel) break;
        }
        float lp = 0.f;
        for (int e = 0; e < 16; ++e) {
            gate_out[(size_t)bt * 16 + e] = gate[e];
            if (gate[e] > 0.f) lp += fmaxf(logf(pr[e]), -10.f);
        }
        lp_out[bt] = lp;
        for (int e = 1; e < 16; ++e)
            if (gate[e] > 0.f) {
                int k = e - 1;
                int p = atomicAdd(&cnt[k], 1);
                list[k * BT_TOT + p] = bt;
                pos[k * BT_TOT + bt] = p;
            }
    }
    float tot = redS[0] + redS[1] + redS[2] + redS[3];
    float r = rsqrtf(tot / (float)ND + 1e-8f);
#pragma unroll
    for (int w = 0; w < 8; ++w)
        xn[(size_t)bt * ND + tid + w * 256] = __float2bfloat16(v[w] * r);
}

// offsets rounded to 128 so BM=128 tile tails never cross expert segments
__global__ void scan_kernel(const int* __restrict__ cnt, int* __restrict__ offs) {
    if (threadIdx.x == 0) {
        int a = 0;
        for (int k = 0; k < KEXP; ++k) { offs[k] = a; a += (cnt[k] + 127) & ~127; }
        offs[KEXP] = a;
    }
}

// ---------------- phi_eff -> bf16 [384][2048], norm_w folded ----------------
__global__ __launch_bounds__(256) void cvt_phi_kernel(
    const float* __restrict__ norm_w, const float* __restrict__ phi_pre,
    const float* __restrict__ phi_post, const float* __restrict__ phi_res,
    __hip_bfloat16* __restrict__ phi_all)
{
    int idx = blockIdx.x * 256 + threadIdx.x;
    int row = idx >> 11, col = idx & 2047;
    float v = 0.f;
    if (row < PHI_ROWS) {
        int k = row / 24, j = row - k * 24, e = k + 1;
        float nw = norm_w[(size_t)e * ND + col];
        float p;
        if (j < 4)      p = phi_pre[((size_t)e * 4 + j) * ND + col];
        else if (j < 8) p = phi_post[((size_t)e * 4 + (j - 4)) * ND + col];
        else            p = phi_res[((size_t)e * 16 + (j - 8)) * ND + col];
        v = p * nw;
    }
    phi_all[idx] = __float2bfloat16(v);
}

// ---------------- single fused weight convert (all 5 types) ----------------
__global__ __launch_bounds__(256) void cvt_all_kernel(
    const float* __restrict__ wd, const float* __restrict__ wu,
    const float* __restrict__ gate, const float* __restrict__ up,
    const float* __restrict__ down, __hip_bfloat16* __restrict__ wbuf, int e0)
{
    int z = blockIdx.z;
    int type = blockIdx.y;
    int g = blockIdx.x * 256 + threadIdx.x;
    int e = e0 + z;
    __hip_bfloat16* dstb = wbuf + (size_t)z * EXPW;
    float4 v = make_float4(0.f, 0.f, 0.f, 0.f);
    size_t didx;
    if (type <= 1) {
        if (g >= 65536) return;
        didx = (type == 0 ? WD_OFF : WU_OFF) + (size_t)g * 4;
        const float* src = (type == 0 ? wd : wu) + (size_t)e * 262144;
        v = *(const float4*)(src + (size_t)g * 4);
    } else if (type <= 3) {
        if (g >= 114688) return;
        size_t idx4 = (size_t)g * 4;
        didx = (type == 2 ? GATE_OFF : UP_OFF) + idx4;
        if (idx4 < (size_t)DFFN * 512) {
            const float* src = (type == 2 ? gate : up) + (size_t)e * DFFN * 512;
            v = *(const float4*)(src + idx4);
        }
    } else {
        if (g >= 114688) return;
        int r = g / 224, gc = g - r * 224;
        didx = DOWN_OFF + (size_t)g * 4;
        if (gc < 207)
            v = *(const float4*)(down + (size_t)e * 512 * DFFN + (size_t)r * DFFN + gc * 4);
    }
    ushort4 o;
    o.x = bf16b_(v.x); o.y = bf16b_(v.y); o.z = bf16b_(v.z); o.w = bf16b_(v.w);
    *(ushort4*)((unsigned short*)dstb + didx) = o;
}

// ---------------- dense 128x128 MFMA GEMM (phi projections, split-K atomic) ----------------
#define LDSS 40
__global__ __launch_bounds__(256) void gemm_dense(
    const __hip_bfloat16* __restrict__ A, const __hip_bfloat16* __restrict__ W,
    float* __restrict__ Cf, int Ka, int Oc, int kLen, int kzStride)
{
    __shared__ __align__(16) unsigned short As[128 * LDSS];
    __shared__ __align__(16) unsigned short Ws[128 * LDSS];
    int z = blockIdx.z;
    int bo = blockIdx.x * 128;
    int bm = blockIdx.y * 128;
    int kbeg = z * kzStride;
    int tid = threadIdx.x;
    int wid = tid >> 6, lane = tid & 63;
    int quad = lane >> 4, lr = lane & 15;
    int wm = (wid & 1) * 64, wn = (wid >> 1) * 64;
    int srow = tid >> 2;
    int schk = (tid & 3) * 8;

    floatx4 acc[4][4];
#pragma unroll
    for (int i = 0; i < 4; ++i)
#pragma unroll
        for (int j = 0; j < 4; ++j) { floatx4 zv = {0.f, 0.f, 0.f, 0.f}; acc[i][j] = zv; }

    for (int k0 = kbeg; k0 < kbeg + kLen; k0 += BK) {
        float4 a0 = *(const float4*)(A + (size_t)(bm + srow) * Ka + k0 + schk);
        float4 a1 = *(const float4*)(A + (size_t)(bm + srow + 64) * Ka + k0 + schk);
        float4 w0 = *(const float4*)(W + (size_t)(bo + srow) * Ka + k0 + schk);
        float4 w1 = *(const float4*)(W + (size_t)(bo + srow + 64) * Ka + k0 + schk);
        __syncthreads();
        *(float4*)&As[srow * LDSS + schk] = a0;
        *(float4*)&As[(srow + 64) * LDSS + schk] = a1;
        *(float4*)&Ws[srow * LDSS + schk] = w0;
        *(float4*)&Ws[(srow + 64) * LDSS + schk] = w1;
        __syncthreads();
        short8 af[4], bf[4];
#pragma unroll
        for (int mi = 0; mi < 4; ++mi)
            af[mi] = *(const short8*)&As[(wm + mi * 16 + lr) * LDSS + quad * 8];
#pragma unroll
        for (int ni = 0; ni < 4; ++ni)
            bf[ni] = *(const short8*)&Ws[(wn + ni * 16 + lr) * LDSS + quad * 8];
#pragma unroll
        for (int mi = 0; mi < 4; ++mi)
#pragma unroll
            for (int ni = 0; ni < 4; ++ni)
                acc[mi][ni] = __builtin_amdgcn_mfma_f32_16x16x32_bf16(
                    af[mi], bf[ni], acc[mi][ni], 0, 0, 0);
    }
#pragma unroll
    for (int mi = 0; mi < 4; ++mi) {
        int row0 = bm + wm + mi * 16 + quad * 4;
#pragma unroll
        for (int ni = 0; ni < 4; ++ni) {
            int col = bo + wn + ni * 16 + lr;
#pragma unroll
            for (int r = 0; r < 4; ++r)
                atomicAdd(&Cf[(size_t)(row0 + r) * Oc + col], acc[mi][ni][r]);
        }
    }
}

// ---------------- stage A: s1 = silu(h@wd^T) || t = silu(h@gate^T)*(h@up^T) ----------------
// BM=128, BN=128, 512 threads (8 waves: 4 m x 2 n), async staging, XOR swizzle
__global__ __launch_bounds__(512) void gemm_stage1(
    const __hip_bfloat16* __restrict__ hA, const __hip_bfloat16* __restrict__ wbuf,
    __hip_bfloat16* __restrict__ s1A, __hip_bfloat16* __restrict__ tA,
    const int* __restrict__ cnt, const int* __restrict__ offs, int kg)
{
    __shared__ __align__(16) unsigned short As[128 * 32];
    __shared__ __align__(16) unsigned short Gs[128 * 32];
    __shared__ __align__(16) unsigned short Us[128 * 32];
    int z = blockIdx.z;
    int k = kg + z;
    int bm = blockIdx.y * 128;
    if (bm >= cnt[k]) return;
    int base = offs[k];
    bool dual = (blockIdx.x >= 4);
    int bo = (dual ? (blockIdx.x - 4) : blockIdx.x) * 128;
    const __hip_bfloat16* Ab = hA + (size_t)base * D_H;
    const __hip_bfloat16* W1 = wbuf + (size_t)z * EXPW + (dual ? GATE_OFF : WD_OFF);
    const __hip_bfloat16* W2 = wbuf + (size_t)z * EXPW + UP_OFF;
    int tid = threadIdx.x;
    int wid = tid >> 6, lane = tid & 63;
    int quad = lane >> 4, lr = lane & 15;
    int lrow = lane >> 2, lchk = lane & 3;
    int achk = lchk ^ ((lrow >> 1) & 3);
    int fs = quad ^ ((lr >> 1) & 3);
    int wm = (wid & 3) * 32, wn = (wid >> 2) * 64;
    int srow = wid * 16 + lrow;          // 0..127
    int ldsb = wid * 512;                // shorts: 16 rows x 32

    floatx4 a1[2][4], a2[2][4];
#pragma unroll
    for (int i = 0; i < 2; ++i)
#pragma unroll
        for (int j = 0; j < 4; ++j) {
            floatx4 zv = {0.f, 0.f, 0.f, 0.f};
            a1[i][j] = zv; a2[i][j] = zv;
        }

    const size_t aoff = (size_t)(bm + srow) * D_H + achk * 8;
    const size_t woff = (size_t)(bo + srow) * D_H + achk * 8;

    for (int k0 = 0; k0 < D_H; k0 += BK) {
        __syncthreads();
        gload16(Ab + aoff + k0, As + ldsb);
        gload16(W1 + woff + k0, Gs + ldsb);
        if (dual) gload16(W2 + woff + k0, Us + ldsb);
        __syncthreads();
        short8 af[2], bg[4];
#pragma unroll
        for (int mi = 0; mi < 2; ++mi)
            af[mi] = *(const short8*)&As[(wm + mi * 16 + lr) * 32 + fs * 8];
#pragma unroll
        for (int ni = 0; ni < 4; ++ni)
            bg[ni] = *(const short8*)&Gs[(wn + ni * 16 + lr) * 32 + fs * 8];
#pragma unroll
        for (int mi = 0; mi < 2; ++mi)
#pragma unroll
            for (int ni = 0; ni < 4; ++ni)
                a1[mi][ni] = __builtin_amdgcn_mfma_f32_16x16x32_bf16(
                    af[mi], bg[ni], a1[mi][ni], 0, 0, 0);
        if (dual) {
            short8 bu[4];
#pragma unroll
            for (int ni = 0; ni < 4; ++ni)
                bu[ni] = *(const short8*)&Us[(wn + ni * 16 + lr) * 32 + fs * 8];
#pragma unroll
            for (int mi = 0; mi < 2; ++mi)
#pragma unroll
                for (int ni = 0; ni < 4; ++ni)
                    a2[mi][ni] = __builtin_amdgcn_mfma_f32_16x16x32_bf16(
                        af[mi], bu[ni], a2[mi][ni], 0, 0, 0);
        }
    }

#pragma unroll
    for (int mi = 0; mi < 2; ++mi) {
        int row0 = bm + wm + mi * 16 + quad * 4;
#pragma unroll
        for (int ni = 0; ni < 4; ++ni) {
            int col = bo + wn + ni * 16 + lr;
#pragma unroll
            for (int r = 0; r < 4; ++r) {
                float v = a1[mi][ni][r];
                if (dual) {
                    float uu = a2[mi][ni][r];
                    tA[(size_t)(base + row0 + r) * DFFN_P + col] =
                        __float2bfloat16(v * sigmoidf_(v) * uu);
                } else {
                    s1A[(size_t)(base + row0 + r) * D_H + col] =
                        __float2bfloat16(v * sigmoidf_(v));
                }
            }
        }
    }
}

// ---------------- final: oute = sigmoid(s1@wu^T) * (t@down^T), two K-phases ----------------
__global__ __launch_bounds__(512) void gemm_final(
    const __hip_bfloat16* __restrict__ s1A, const __hip_bfloat16* __restrict__ tA,
    const __hip_bfloat16* __restrict__ wbuf, __hip_bfloat16* __restrict__ outeA,
    const int* __restrict__ cnt, const int* __restrict__ offs, int kg)
{
    __shared__ __align__(16) unsigned short As[128 * 32];
    __shared__ __align__(16) unsigned short Ws[128 * 32];
    int z = blockIdx.z;
    int k = kg + z;
    int bm = blockIdx.y * 128;
    if (bm >= cnt[k]) return;
    int base = offs[k];
    int bo = blockIdx.x * 128;
    const __hip_bfloat16* A1 = s1A + (size_t)base * D_H;
    const __hip_bfloat16* A2 = tA + (size_t)base * DFFN_P;
    const __hip_bfloat16* Wu = wbuf + (size_t)z * EXPW + WU_OFF;
    const __hip_bfloat16* Wd = wbuf + (size_t)z * EXPW + DOWN_OFF;
    int tid = threadIdx.x;
    int wid = tid >> 6, lane = tid & 63;
    int quad = lane >> 4, lr = lane & 15;
    int lrow = lane >> 2, lchk = lane & 3;
    int achk = lchk ^ ((lrow >> 1) & 3);
    int fs = quad ^ ((lr >> 1) & 3);
    int wm = (wid & 3) * 32, wn = (wid >> 2) * 64;
    int srow = wid * 16 + lrow;
    int ldsb = wid * 512;

    floatx4 accg[2][4], accd[2][4];
#pragma unroll
    for (int i = 0; i < 2; ++i)
#pragma unroll
        for (int j = 0; j < 4; ++j) {
            floatx4 zv = {0.f, 0.f, 0.f, 0.f};
            accg[i][j] = zv; accd[i][j] = zv;
        }

    // phase 1: g over K=512 (s1 @ wu^T)
    for (int k0 = 0; k0 < D_H; k0 += BK) {
        __syncthreads();
        gload16(A1 + (size_t)(bm + srow) * D_H + k0 + achk * 8, As + ldsb);
        gload16(Wu + (size_t)(bo + srow) * D_H + k0 + achk * 8, Ws + ldsb);
        __syncthreads();
        short8 af[2], bf[4];
#pragma unroll
        for (int mi = 0; mi < 2; ++mi)
            af[mi] = *(const short8*)&As[(wm + mi * 16 + lr) * 32 + fs * 8];
#pragma unroll
        for (int ni = 0; ni < 4; ++ni)
            bf[ni] = *(const short8*)&Ws[(wn + ni * 16 + lr) * 32 + fs * 8];
#pragma unroll
        for (int mi = 0; mi < 2; ++mi)
#pragma unroll
            for (int ni = 0; ni < 4; ++ni)
                accg[mi][ni] = __builtin_amdgcn_mfma_f32_16x16x32_bf16(
                    af[mi], bf[ni], accg[mi][ni], 0, 0, 0);
    }
    // phase 2: d over K=896 (t @ down^T)
    for (int k0 = 0; k0 < DFFN_P; k0 += BK) {
        __syncthreads();
        gload16(A2 + (size_t)(bm + srow) * DFFN_P + k0 + achk * 8, As + ldsb);
        gload16(Wd + (size_t)(bo + srow) * DFFN_P + k0 + achk * 8, Ws + ldsb);
        __syncthreads();
        short8 af[2], bf[4];
#pragma unroll
        for (int mi = 0; mi < 2; ++mi)
            af[mi] = *(const short8*)&As[(wm + mi * 16 + lr) * 32 + fs * 8];
#pragma unroll
        for (int ni = 0; ni < 4; ++ni)
            bf[ni] = *(const short8*)&Ws[(wn + ni * 16 + lr) * 32 + fs * 8];
#pragma unroll
        for (int mi = 0; mi < 2; ++mi)
#pragma unroll
            for (int ni = 0; ni < 4; ++ni)
                accd[mi][ni] = __builtin_amdgcn_mfma_f32_16x16x32_bf16(
                    af[mi], bf[ni], accd[mi][ni], 0, 0, 0);
    }

#pragma unroll
    for (int mi = 0; mi < 2; ++mi) {
        int row0 = bm + wm + mi * 16 + quad * 4;
#pragma unroll
        for (int ni = 0; ni < 4; ++ni) {
            int col = bo + wn + ni * 16 + lr;
#pragma unroll
            for (int r = 0; r < 4; ++r) {
                float g = accg[mi][ni][r];
                float d = accd[mi][ni][r];
                outeA[(size_t)(base + row0 + r) * D_H + col] =
                    __float2bfloat16(sigmoidf_(g) * d);
            }
        }
    }
}

// ---------------- h (compacted) + inline sigmoid/sinkhorn ----------------
__global__ __launch_bounds__(256) void h_kernel(
    const float* __restrict__ stream, const float* __restrict__ Cproj,
    const float* __restrict__ b_pre, const float* __restrict__ b_post,
    const float* __restrict__ b_res, const float* __restrict__ a_pre,
    const float* __restrict__ a_post, const float* __restrict__ a_res,
    const float* __restrict__ sw_norm, const int* __restrict__ list,
    const int* __restrict__ counts, const int* __restrict__ offs,
    __hip_bfloat16* __restrict__ hA, float* __restrict__ Hpost,
    float* __restrict__ Hres)
{
    int k = blockIdx.y;
    int i = blockIdx.x;
    if (i >= counts[k]) return;
    int bt = list[k * BT_TOT + i];
    int e = k + 1;
    int b = bt >> 10, t = bt & 1023;
    int tid = threadIdx.x;
    __shared__ float HpreS[4];
    if (tid == 0) {
        const float* s = Cproj + (size_t)bt * PHI_ROWS_P + k * 24;
        float ap = a_pre[e], aq = a_post[e], ar = a_res[e];
#pragma unroll
        for (int n = 0; n < 4; ++n)
            HpreS[n] = sigmoidf_(ap * s[n] + b_pre[e * 4 + n]);
#pragma unroll
        for (int n = 0; n < 4; ++n)
            Hpost[((size_t)k * BT_TOT + bt) * 4 + n] =
                2.f * sigmoidf_(aq * s[4 + n] + b_post[e * 4 + n]);
        float M[16];
#pragma unroll
        for (int j = 0; j < 16; ++j) M[j] = expf(ar * s[8 + j] + b_res[e * 16 + j]);
#pragma unroll
        for (int it = 0; it < 6; ++it) {
#pragma unroll
            for (int r = 0; r < 4; ++r) {
                float iv = 1.f / (M[r*4] + M[r*4+1] + M[r*4+2] + M[r*4+3]);
                M[r*4] *= iv; M[r*4+1] *= iv; M[r*4+2] *= iv; M[r*4+3] *= iv;
            }
#pragma unroll
            for (int c = 0; c < 4; ++c) {
                float iv = 1.f / (M[c] + M[4+c] + M[8+c] + M[12+c]);
                M[c] *= iv; M[4+c] *= iv; M[8+c] *= iv; M[12+c] *= iv;
            }
        }
#pragma unroll
        for (int j = 0; j < 16; ++j) Hres[((size_t)k * BT_TOT + bt) * 16 + j] = M[j];
    }
    __syncthreads();
    float hp[4];
#pragma unroll
    for (int n = 0; n < 4; ++n) hp[n] = HpreS[n];
    float he[2]; float ss = 0.f;
#pragma unroll
    for (int w = 0; w < 2; ++w) {
        int d = tid + w * 256;
        float v = 0.f;
#pragma unroll
        for (int n = 0; n < 4; ++n)
            v += hp[n] * stream[(((size_t)b * 4 + n) * T_LEN + t) * D_H + d];
        he[w] = v; ss += v * v;
    }
#pragma unroll
    for (int off = 32; off; off >>= 1) ss += __shfl_down(ss, off, 64);
    __shared__ float red[4];
    int wave = tid >> 6, lane = tid & 63;
    if (lane == 0) red[wave] = ss;
    __syncthreads();
    float tot = red[0] + red[1] + red[2] + red[3];
    float r = rsqrtf(tot / (float)D_H + 1e-8f);
    size_t row = (size_t)(offs[k] + i);
#pragma unroll
    for (int w = 0; w < 2; ++w) {
        int d = tid + w * 256;
        hA[row * D_H + d] = __float2bfloat16(he[w] * r * sw_norm[(size_t)e * D_H + d]);
    }
}

// ---------------- combine: out = sum_k gate*(H_res@stream + H_post*oute) ----------------
__global__ __launch_bounds__(256) void combine_kernel(
    const float* __restrict__ stream, const __hip_bfloat16* __restrict__ outeA,
    const float* __restrict__ Hpost, const float* __restrict__ Hres,
    const float* __restrict__ gate_all, const int* __restrict__ pos,
    const int* __restrict__ offs, float* __restrict__ out)
{
    int bt = blockIdx.x; int b = bt >> 10; int t = bt & 1023;
    int tid = threadIdx.x;
    float s[2][4], accv[2][4];
#pragma unroll
    for (int w = 0; w < 2; ++w) {
        int d = tid + w * 256;
#pragma unroll
        for (int n = 0; n < 4; ++n) {
            s[w][n] = stream[(((size_t)b * 4 + n) * T_LEN + t) * D_H + d];
            accv[w][n] = 0.f;
        }
    }
    for (int k = 0; k < KEXP; ++k) {
        float gate = gate_all[(size_t)bt * 16 + k + 1];
        if (gate == 0.f) continue;
        size_t row = (size_t)(offs[k] + pos[k * BT_TOT + bt]);
        float hr[16], hp[4];
#pragma unroll
        for (int i = 0; i < 16; ++i) hr[i] = Hres[((size_t)k * BT_TOT + bt) * 16 + i];
#pragma unroll
        for (int i = 0; i < 4; ++i) hp[i] = Hpost[((size_t)k * BT_TOT + bt) * 4 + i];
#pragma unroll
        for (int w = 0; w < 2; ++w) {
            int d = tid + w * 256;
            float oe = __bfloat162float(outeA[row * D_H + d]);
#pragma unroll
            for (int i = 0; i < 4; ++i) {
                float v = hp[i] * oe + hr[i*4+0]*s[w][0] + hr[i*4+1]*s[w][1]
                        + hr[i*4+2]*s[w][2] + hr[i*4+3]*s[w][3];
                accv[w][i] += gate * v;
            }
        }
    }
#pragma unroll
    for (int w = 0; w < 2; ++w) {
        int d = tid + w * 256;
#pragma unroll
        for (int i = 0; i < 4; ++i)
            out[(((size_t)b * 4 + i) * T_LEN + t) * D_H + d] = accv[w][i];
    }
}

extern "C" void kernel_launch(void* const* d_in, const int* in_sizes, int n_in,
                              void* d_out, int out_size, void* d_ws, size_t ws_size,
                              hipStream_t stream) {
    const float* stream_in = (const float*)d_in[0];
    const float* norm_w    = (const float*)d_in[1];
    const float* phi_pre   = (const float*)d_in[2];
    const float* phi_post  = (const float*)d_in[3];
    const float* phi_res   = (const float*)d_in[4];
    const float* b_pre     = (const float*)d_in[5];
    const float* b_post    = (const float*)d_in[6];
    const float* b_res     = (const float*)d_in[7];
    const float* alpha_pre = (const float*)d_in[8];
    const float* alpha_post= (const float*)d_in[9];
    const float* alpha_res = (const float*)d_in[10];
    const float* sw_norm   = (const float*)d_in[11];
    const float* wd_w      = (const float*)d_in[12];
    const float* wu_w      = (const float*)d_in[13];
    const float* gate_w    = (const float*)d_in[14];
    const float* up_w      = (const float*)d_in[15];
    const float* down_w    = (const float*)d_in[16];
    const float* router_w  = (const float*)d_in[17];

    float* out = (float*)d_out;
    const int SU_N = 2 * 4 * T_LEN * D_H;
    float* gate_out = out + SU_N;
    float* lp_out = gate_out + BT_TOT * 16;

    // ---- workspace carve-up ----
    char* p = (char*)d_ws;
    __hip_bfloat16* xn     = (__hip_bfloat16*)p; p += (size_t)BT_TOT * ND * 2;
    __hip_bfloat16* phiall = (__hip_bfloat16*)p; p += (size_t)PHI_ROWS_P * ND * 2;
    float* Cproj = (float*)p; p += (size_t)BT_TOT * PHI_ROWS_P * 4;
    float* Hpost = (float*)p; p += (size_t)KEXP * BT_TOT * 4 * 4;
    float* Hres  = (float*)p; p += (size_t)KEXP * BT_TOT * 16 * 4;
    int* cnt  = (int*)p; p += 256;
    int* offs = (int*)p; p += 256;
    int* list = (int*)p; p += (size_t)KEXP * BT_TOT * 4;
    int* pos  = (int*)p; p += (size_t)KEXP * BT_TOT * 4;
    __hip_bfloat16* hA    = (__hip_bfloat16*)p; p += (size_t)PAIR_CAP * D_H * 2;
    __hip_bfloat16* s1A   = (__hip_bfloat16*)p; p += (size_t)PAIR_CAP * D_H * 2;
    __hip_bfloat16* outeA = (__hip_bfloat16*)p; p += (size_t)PAIR_CAP * D_H * 2;
    __hip_bfloat16* tA    = (__hip_bfloat16*)p; p += (size_t)PAIR_CAP * DFFN_P * 2;
    size_t fixed_bytes = (size_t)(p - (char*)d_ws);
    size_t perW = (size_t)EXPW * 2;
    size_t avail = ws_size > fixed_bytes ? ws_size - fixed_bytes : 0;
    int G = (int)(avail / perW);
    if (G > KEXP) G = KEXP;
    if (G < 1) G = 1;
    __hip_bfloat16* wbuf = (__hip_bfloat16*)p;

    // ---- prologue ----
    hipMemsetAsync(cnt, 0, 64, stream);
    hipMemsetAsync(Cproj, 0, (size_t)BT_TOT * PHI_ROWS_P * 4, stream);
    prep_kernel<<<BT_TOT, 256, 0, stream>>>(
        stream_in, router_w, xn, gate_out, lp_out, cnt, list, pos);
    scan_kernel<<<1, 64, 0, stream>>>(cnt, offs);
    cvt_phi_kernel<<<(PHI_ROWS_P * ND) / 256, 256, 0, stream>>>(
        norm_w, phi_pre, phi_post, phi_res, phiall);
    gemm_dense<<<dim3(3, 16, 4), 256, 0, stream>>>(
        xn, phiall, Cproj, ND, PHI_ROWS_P, 512, 512);
    h_kernel<<<dim3(BT_TOT, KEXP), 256, 0, stream>>>(
        stream_in, Cproj, b_pre, b_post, b_res, alpha_pre, alpha_post, alpha_res,
        sw_norm, list, cnt, offs, hA, Hpost, Hres);

    // ---- expert weight groups ----
    for (int kg = 0; kg < KEXP; kg += G) {
        int Gc = (kg + G <= KEXP) ? G : (KEXP - kg);
        int e0 = kg + 1;
        cvt_all_kernel<<<dim3(448, 5, Gc), 256, 0, stream>>>(
            wd_w, wu_w, gate_w, up_w, down_w, wbuf, e0);
        // s1 = silu(h@wd^T)  ||  t = silu(h@gate^T)*(h@up^T)
        gemm_stage1<<<dim3(11, 16, Gc), 512, 0, stream>>>(
            hA, wbuf, s1A, tA, cnt, offs, kg);
        // oute = sigmoid(s1@wu^T) * (t@down^T)
        gemm_final<<<dim3(4, 16, Gc), 512, 0, stream>>>(
            s1A, tA, wbuf, outeA, cnt, offs, kg);
    }

    combine_kernel<<<BT_TOT, 256, 0, stream>>>(
        stream_in, outeA, Hpost, Hres, gate_out, pos, offs, out);
}

// Round 7
// 401.487 us; speedup vs baseline: 1.1255x; 1.1255x over previous
//
#include <hip/hip_runtime.h>
#include <hip/hip_bf16.h>
#include <math.h>

typedef __attribute__((ext_vector_type(8))) short short8;
typedef __attribute__((ext_vector_type(4))) float floatx4;

#define T_LEN 1024
#define D_H 512
#define ND 2048
#define KEXP 15
#define DFFN 828
#define DFFN_P 896
#define BT_TOT 2048
#define PHI_ROWS 360
#define PHI_ROWS_P 384
#define PAIR_CAP 10240  // sum of per-expert 128-rounded counts <= 8192+15*127

// per-expert packed bf16 weight layout (elements)
#define WD_OFF   0
#define WU_OFF   262144
#define GATE_OFF 524288
#define UP_OFF   983040
#define DOWN_OFF 1441792
#define EXPW     1900544

#define BK 32

__device__ __forceinline__ float sigmoidf_(float x) { return 1.f / (1.f + expf(-x)); }
__device__ __forceinline__ unsigned short bf16b_(float x) {
    __hip_bfloat16 h = __float2bfloat16(x);
    return *reinterpret_cast<unsigned short*>(&h);
}

// async global->LDS, 16B per lane; LDS dest = wave-uniform base + lane*16
__device__ __forceinline__ void gload16(const __hip_bfloat16* g, unsigned short* l) {
    __builtin_amdgcn_global_load_lds(
        (const __attribute__((address_space(1))) void*)(uintptr_t)g,
        (__attribute__((address_space(3))) void*)(unsigned int)(uintptr_t)l,
        16, 0, 0);
}

// ---------------- router + list build (wave-parallel atomics — do NOT serialize
// through one thread: cross-XCD hot-line atomics cost ~95us that way, r6 lesson) ----------------
__global__ __launch_bounds__(64) void router_kernel(
    const float* __restrict__ stream, const float* __restrict__ rw,
    float* __restrict__ gate_out, float* __restrict__ lp_out,
    int* __restrict__ cnt, int* __restrict__ list, int* __restrict__ pos)
{
    int bt = blockIdx.x; int b = bt >> 10; int t = bt & 1023;
    int lane = threadIdx.x;
    float ri[8];
#pragma unroll
    for (int w = 0; w < 8; ++w) {
        int d = lane + w * 64;
        float s = 0.f;
#pragma unroll
        for (int n = 0; n < 4; ++n)
            s += stream[(((size_t)b * 4 + n) * T_LEN + t) * D_H + d];
        ri[w] = 0.25f * s;
    }
    float logits[16];
    for (int e = 0; e < 16; ++e) {
        float p = 0.f;
#pragma unroll
        for (int w = 0; w < 8; ++w) p += ri[w] * rw[e * D_H + lane + w * 64];
#pragma unroll
        for (int off = 32; off; off >>= 1) p += __shfl_xor(p, off, 64);
        logits[e] = p;
    }
    float mx = logits[0];
    for (int e = 1; e < 16; ++e) mx = fmaxf(mx, logits[e]);
    float pr[16]; float sum = 0.f;
    for (int e = 0; e < 16; ++e) { pr[e] = expf(logits[e] - mx); sum += pr[e]; }
    float inv = 1.f / sum;
    for (int e = 0; e < 16; ++e) pr[e] *= inv;

    float gate[16]; bool taken[16];
    for (int e = 0; e < 16; ++e) { gate[e] = 0.f; taken[e] = false; }
    float prefix = 0.f;
    for (int rank = 0; rank < 4; ++rank) {
        int best = -1; float bp = -1.f;
        for (int e = 0; e < 16; ++e)
            if (!taken[e] && pr[e] > bp) { bp = pr[e]; best = e; }
        taken[best] = true;
        bool sel = (rank == 0) || (prefix < 0.8f);
        if (sel) gate[best] = bp;
        prefix += bp;
        if (!sel) break;
    }
    float lp = 0.f;
    for (int e = 0; e < 16; ++e)
        if (gate[e] > 0.f) lp += fmaxf(logf(pr[e]), -10.f);
    if (lane < 16) gate_out[(size_t)bt * 16 + lane] = gate[lane];
    if (lane == 0) lp_out[bt] = lp;
    if (lane >= 1 && lane < 16 && gate[lane] > 0.f) {
        int k = lane - 1;
        int p = atomicAdd(&cnt[k], 1);
        list[k * BT_TOT + p] = bt;
        pos[k * BT_TOT + bt] = p;
    }
}

// offsets rounded to 128 so BM=128 tile tails never cross expert segments
__global__ void scan_kernel(const int* __restrict__ cnt, int* __restrict__ offs) {
    if (threadIdx.x == 0) {
        int a = 0;
        for (int k = 0; k < KEXP; ++k) { offs[k] = a; a += (cnt[k] + 127) & ~127; }
        offs[KEXP] = a;
    }
}

// ---------------- xn = rmsnorm(x) over nd=2048, bf16 out ----------------
__global__ __launch_bounds__(256) void xn_kernel(
    const float* __restrict__ stream, __hip_bfloat16* __restrict__ xn)
{
    int bt = blockIdx.x; int b = bt >> 10; int t = bt & 1023;
    int tid = threadIdx.x;
    float v[8]; float ss = 0.f;
#pragma unroll
    for (int w = 0; w < 8; ++w) {
        int j = tid + w * 256;
        int n = j >> 9, d = j & 511;
        float x = stream[(((size_t)b * 4 + n) * T_LEN + t) * D_H + d];
        v[w] = x; ss += x * x;
    }
#pragma unroll
    for (int off = 32; off; off >>= 1) ss += __shfl_down(ss, off, 64);
    __shared__ float red[4];
    int wave = tid >> 6, lane = tid & 63;
    if (lane == 0) red[wave] = ss;
    __syncthreads();
    float tot = red[0] + red[1] + red[2] + red[3];
    float r = rsqrtf(tot / (float)ND + 1e-8f);
#pragma unroll
    for (int w = 0; w < 8; ++w)
        xn[(size_t)bt * ND + tid + w * 256] = __float2bfloat16(v[w] * r);
}

// ---------------- phi_eff -> bf16 [384][2048], norm_w folded ----------------
__global__ __launch_bounds__(256) void cvt_phi_kernel(
    const float* __restrict__ norm_w, const float* __restrict__ phi_pre,
    const float* __restrict__ phi_post, const float* __restrict__ phi_res,
    __hip_bfloat16* __restrict__ phi_all)
{
    int idx = blockIdx.x * 256 + threadIdx.x;
    int row = idx >> 11, col = idx & 2047;
    float v = 0.f;
    if (row < PHI_ROWS) {
        int k = row / 24, j = row - k * 24, e = k + 1;
        float nw = norm_w[(size_t)e * ND + col];
        float p;
        if (j < 4)      p = phi_pre[((size_t)e * 4 + j) * ND + col];
        else if (j < 8) p = phi_post[((size_t)e * 4 + (j - 4)) * ND + col];
        else            p = phi_res[((size_t)e * 16 + (j - 8)) * ND + col];
        v = p * nw;
    }
    phi_all[idx] = __float2bfloat16(v);
}

// ---------------- single fused weight convert (all 5 types) ----------------
__global__ __launch_bounds__(256) void cvt_all_kernel(
    const float* __restrict__ wd, const float* __restrict__ wu,
    const float* __restrict__ gate, const float* __restrict__ up,
    const float* __restrict__ down, __hip_bfloat16* __restrict__ wbuf, int e0)
{
    int z = blockIdx.z;
    int type = blockIdx.y;
    int g = blockIdx.x * 256 + threadIdx.x;
    int e = e0 + z;
    __hip_bfloat16* dstb = wbuf + (size_t)z * EXPW;
    float4 v = make_float4(0.f, 0.f, 0.f, 0.f);
    size_t didx;
    if (type <= 1) {
        if (g >= 65536) return;
        didx = (type == 0 ? WD_OFF : WU_OFF) + (size_t)g * 4;
        const float* src = (type == 0 ? wd : wu) + (size_t)e * 262144;
        v = *(const float4*)(src + (size_t)g * 4);
    } else if (type <= 3) {
        if (g >= 114688) return;
        size_t idx4 = (size_t)g * 4;
        didx = (type == 2 ? GATE_OFF : UP_OFF) + idx4;
        if (idx4 < (size_t)DFFN * 512) {
            const float* src = (type == 2 ? gate : up) + (size_t)e * DFFN * 512;
            v = *(const float4*)(src + idx4);
        }
    } else {
        if (g >= 114688) return;
        int r = g / 224, gc = g - r * 224;
        didx = DOWN_OFF + (size_t)g * 4;
        if (gc < 207)
            v = *(const float4*)(down + (size_t)e * 512 * DFFN + (size_t)r * DFFN + gc * 4);
    }
    ushort4 o;
    o.x = bf16b_(v.x); o.y = bf16b_(v.y); o.z = bf16b_(v.z); o.w = bf16b_(v.w);
    *(ushort4*)((unsigned short*)dstb + didx) = o;
}

// ---------------- dense 128x128 MFMA GEMM (phi projections, split-K=8 atomic) ----------------
#define LDSS 40
__global__ __launch_bounds__(256) void gemm_dense(
    const __hip_bfloat16* __restrict__ A, const __hip_bfloat16* __restrict__ W,
    float* __restrict__ Cf, int Ka, int Oc, int kLen, int kzStride)
{
    __shared__ __align__(16) unsigned short As[128 * LDSS];
    __shared__ __align__(16) unsigned short Ws[128 * LDSS];
    int z = blockIdx.z;
    int bo = blockIdx.x * 128;
    int bm = blockIdx.y * 128;
    int kbeg = z * kzStride;
    int tid = threadIdx.x;
    int wid = tid >> 6, lane = tid & 63;
    int quad = lane >> 4, lr = lane & 15;
    int wm = (wid & 1) * 64, wn = (wid >> 1) * 64;
    int srow = tid >> 2;
    int schk = (tid & 3) * 8;

    floatx4 acc[4][4];
#pragma unroll
    for (int i = 0; i < 4; ++i)
#pragma unroll
        for (int j = 0; j < 4; ++j) { floatx4 zv = {0.f, 0.f, 0.f, 0.f}; acc[i][j] = zv; }

    for (int k0 = kbeg; k0 < kbeg + kLen; k0 += BK) {
        float4 a0 = *(const float4*)(A + (size_t)(bm + srow) * Ka + k0 + schk);
        float4 a1 = *(const float4*)(A + (size_t)(bm + srow + 64) * Ka + k0 + schk);
        float4 w0 = *(const float4*)(W + (size_t)(bo + srow) * Ka + k0 + schk);
        float4 w1 = *(const float4*)(W + (size_t)(bo + srow + 64) * Ka + k0 + schk);
        __syncthreads();
        *(float4*)&As[srow * LDSS + schk] = a0;
        *(float4*)&As[(srow + 64) * LDSS + schk] = a1;
        *(float4*)&Ws[srow * LDSS + schk] = w0;
        *(float4*)&Ws[(srow + 64) * LDSS + schk] = w1;
        __syncthreads();
        short8 af[4], bf[4];
#pragma unroll
        for (int mi = 0; mi < 4; ++mi)
            af[mi] = *(const short8*)&As[(wm + mi * 16 + lr) * LDSS + quad * 8];
#pragma unroll
        for (int ni = 0; ni < 4; ++ni)
            bf[ni] = *(const short8*)&Ws[(wn + ni * 16 + lr) * LDSS + quad * 8];
#pragma unroll
        for (int mi = 0; mi < 4; ++mi)
#pragma unroll
            for (int ni = 0; ni < 4; ++ni)
                acc[mi][ni] = __builtin_amdgcn_mfma_f32_16x16x32_bf16(
                    af[mi], bf[ni], acc[mi][ni], 0, 0, 0);
    }
#pragma unroll
    for (int mi = 0; mi < 4; ++mi) {
        int row0 = bm + wm + mi * 16 + quad * 4;
#pragma unroll
        for (int ni = 0; ni < 4; ++ni) {
            int col = bo + wn + ni * 16 + lr;
#pragma unroll
            for (int r = 0; r < 4; ++r)
                atomicAdd(&Cf[(size_t)(row0 + r) * Oc + col], acc[mi][ni][r]);
        }
    }
}

// ---------------- stage A: s1 = silu(h@wd^T) || t = silu(h@gate^T)*(h@up^T) ----------------
// BM=128, BN=128, 512 threads (8 waves: 4 m x 2 n), async staging, XOR swizzle
__global__ __launch_bounds__(512) void gemm_stage1(
    const __hip_bfloat16* __restrict__ hA, const __hip_bfloat16* __restrict__ wbuf,
    __hip_bfloat16* __restrict__ s1A, __hip_bfloat16* __restrict__ tA,
    const int* __restrict__ cnt, const int* __restrict__ offs, int kg)
{
    __shared__ __align__(16) unsigned short As[128 * 32];
    __shared__ __align__(16) unsigned short Gs[128 * 32];
    __shared__ __align__(16) unsigned short Us[128 * 32];
    int z = blockIdx.z;
    int k = kg + z;
    int bm = blockIdx.y * 128;
    if (bm >= cnt[k]) return;
    int base = offs[k];
    bool dual = (blockIdx.x >= 4);
    int bo = (dual ? (blockIdx.x - 4) : blockIdx.x) * 128;
    const __hip_bfloat16* Ab = hA + (size_t)base * D_H;
    const __hip_bfloat16* W1 = wbuf + (size_t)z * EXPW + (dual ? GATE_OFF : WD_OFF);
    const __hip_bfloat16* W2 = wbuf + (size_t)z * EXPW + UP_OFF;
    int tid = threadIdx.x;
    int wid = tid >> 6, lane = tid & 63;
    int quad = lane >> 4, lr = lane & 15;
    int lrow = lane >> 2, lchk = lane & 3;
    int achk = lchk ^ ((lrow >> 1) & 3);
    int fs = quad ^ ((lr >> 1) & 3);
    int wm = (wid & 3) * 32, wn = (wid >> 2) * 64;
    int srow = wid * 16 + lrow;          // 0..127
    int ldsb = wid * 512;                // shorts: 16 rows x 32

    floatx4 a1[2][4], a2[2][4];
#pragma unroll
    for (int i = 0; i < 2; ++i)
#pragma unroll
        for (int j = 0; j < 4; ++j) {
            floatx4 zv = {0.f, 0.f, 0.f, 0.f};
            a1[i][j] = zv; a2[i][j] = zv;
        }

    const size_t aoff = (size_t)(bm + srow) * D_H + achk * 8;
    const size_t woff = (size_t)(bo + srow) * D_H + achk * 8;

    for (int k0 = 0; k0 < D_H; k0 += BK) {
        __syncthreads();
        gload16(Ab + aoff + k0, As + ldsb);
        gload16(W1 + woff + k0, Gs + ldsb);
        if (dual) gload16(W2 + woff + k0, Us + ldsb);
        __syncthreads();
        short8 af[2], bg[4];
#pragma unroll
        for (int mi = 0; mi < 2; ++mi)
            af[mi] = *(const short8*)&As[(wm + mi * 16 + lr) * 32 + fs * 8];
#pragma unroll
        for (int ni = 0; ni < 4; ++ni)
            bg[ni] = *(const short8*)&Gs[(wn + ni * 16 + lr) * 32 + fs * 8];
#pragma unroll
        for (int mi = 0; mi < 2; ++mi)
#pragma unroll
            for (int ni = 0; ni < 4; ++ni)
                a1[mi][ni] = __builtin_amdgcn_mfma_f32_16x16x32_bf16(
                    af[mi], bg[ni], a1[mi][ni], 0, 0, 0);
        if (dual) {
            short8 bu[4];
#pragma unroll
            for (int ni = 0; ni < 4; ++ni)
                bu[ni] = *(const short8*)&Us[(wn + ni * 16 + lr) * 32 + fs * 8];
#pragma unroll
            for (int mi = 0; mi < 2; ++mi)
#pragma unroll
                for (int ni = 0; ni < 4; ++ni)
                    a2[mi][ni] = __builtin_amdgcn_mfma_f32_16x16x32_bf16(
                        af[mi], bu[ni], a2[mi][ni], 0, 0, 0);
        }
    }

#pragma unroll
    for (int mi = 0; mi < 2; ++mi) {
        int row0 = bm + wm + mi * 16 + quad * 4;
#pragma unroll
        for (int ni = 0; ni < 4; ++ni) {
            int col = bo + wn + ni * 16 + lr;
#pragma unroll
            for (int r = 0; r < 4; ++r) {
                float v = a1[mi][ni][r];
                if (dual) {
                    float uu = a2[mi][ni][r];
                    tA[(size_t)(base + row0 + r) * DFFN_P + col] =
                        __float2bfloat16(v * sigmoidf_(v) * uu);
                } else {
                    s1A[(size_t)(base + row0 + r) * D_H + col] =
                        __float2bfloat16(v * sigmoidf_(v));
                }
            }
        }
    }
}

// ---------------- final: oute = sigmoid(s1@wu^T) * (t@down^T), two K-phases ----------------
__global__ __launch_bounds__(512) void gemm_final(
    const __hip_bfloat16* __restrict__ s1A, const __hip_bfloat16* __restrict__ tA,
    const __hip_bfloat16* __restrict__ wbuf, __hip_bfloat16* __restrict__ outeA,
    const int* __restrict__ cnt, const int* __restrict__ offs, int kg)
{
    __shared__ __align__(16) unsigned short As[128 * 32];
    __shared__ __align__(16) unsigned short Ws[128 * 32];
    int z = blockIdx.z;
    int k = kg + z;
    int bm = blockIdx.y * 128;
    if (bm >= cnt[k]) return;
    int base = offs[k];
    int bo = blockIdx.x * 128;
    const __hip_bfloat16* A1 = s1A + (size_t)base * D_H;
    const __hip_bfloat16* A2 = tA + (size_t)base * DFFN_P;
    const __hip_bfloat16* Wu = wbuf + (size_t)z * EXPW + WU_OFF;
    const __hip_bfloat16* Wd = wbuf + (size_t)z * EXPW + DOWN_OFF;
    int tid = threadIdx.x;
    int wid = tid >> 6, lane = tid & 63;
    int quad = lane >> 4, lr = lane & 15;
    int lrow = lane >> 2, lchk = lane & 3;
    int achk = lchk ^ ((lrow >> 1) & 3);
    int fs = quad ^ ((lr >> 1) & 3);
    int wm = (wid & 3) * 32, wn = (wid >> 2) * 64;
    int srow = wid * 16 + lrow;
    int ldsb = wid * 512;

    floatx4 accg[2][4], accd[2][4];
#pragma unroll
    for (int i = 0; i < 2; ++i)
#pragma unroll
        for (int j = 0; j < 4; ++j) {
            floatx4 zv = {0.f, 0.f, 0.f, 0.f};
            accg[i][j] = zv; accd[i][j] = zv;
        }

    // phase 1: g over K=512 (s1 @ wu^T)
    for (int k0 = 0; k0 < D_H; k0 += BK) {
        __syncthreads();
        gload16(A1 + (size_t)(bm + srow) * D_H + k0 + achk * 8, As + ldsb);
        gload16(Wu + (size_t)(bo + srow) * D_H + k0 + achk * 8, Ws + ldsb);
        __syncthreads();
        short8 af[2], bf[4];
#pragma unroll
        for (int mi = 0; mi < 2; ++mi)
            af[mi] = *(const short8*)&As[(wm + mi * 16 + lr) * 32 + fs * 8];
#pragma unroll
        for (int ni = 0; ni < 4; ++ni)
            bf[ni] = *(const short8*)&Ws[(wn + ni * 16 + lr) * 32 + fs * 8];
#pragma unroll
        for (int mi = 0; mi < 2; ++mi)
#pragma unroll
            for (int ni = 0; ni < 4; ++ni)
                accg[mi][ni] = __builtin_amdgcn_mfma_f32_16x16x32_bf16(
                    af[mi], bf[ni], accg[mi][ni], 0, 0, 0);
    }
    // phase 2: d over K=896 (t @ down^T)
    for (int k0 = 0; k0 < DFFN_P; k0 += BK) {
        __syncthreads();
        gload16(A2 + (size_t)(bm + srow) * DFFN_P + k0 + achk * 8, As + ldsb);
        gload16(Wd + (size_t)(bo + srow) * DFFN_P + k0 + achk * 8, Ws + ldsb);
        __syncthreads();
        short8 af[2], bf[4];
#pragma unroll
        for (int mi = 0; mi < 2; ++mi)
            af[mi] = *(const short8*)&As[(wm + mi * 16 + lr) * 32 + fs * 8];
#pragma unroll
        for (int ni = 0; ni < 4; ++ni)
            bf[ni] = *(const short8*)&Ws[(wn + ni * 16 + lr) * 32 + fs * 8];
#pragma unroll
        for (int mi = 0; mi < 2; ++mi)
#pragma unroll
            for (int ni = 0; ni < 4; ++ni)
                accd[mi][ni] = __builtin_amdgcn_mfma_f32_16x16x32_bf16(
                    af[mi], bf[ni], accd[mi][ni], 0, 0, 0);
    }

#pragma unroll
    for (int mi = 0; mi < 2; ++mi) {
        int row0 = bm + wm + mi * 16 + quad * 4;
#pragma unroll
        for (int ni = 0; ni < 4; ++ni) {
            int col = bo + wn + ni * 16 + lr;
#pragma unroll
            for (int r = 0; r < 4; ++r) {
                float g = accg[mi][ni][r];
                float d = accd[mi][ni][r];
                outeA[(size_t)(base + row0 + r) * D_H + col] =
                    __float2bfloat16(sigmoidf_(g) * d);
            }
        }
    }
}

// ---------------- h (compacted) + inline sigmoid/sinkhorn ----------------
__global__ __launch_bounds__(256) void h_kernel(
    const float* __restrict__ stream, const float* __restrict__ Cproj,
    const float* __restrict__ b_pre, const float* __restrict__ b_post,
    const float* __restrict__ b_res, const float* __restrict__ a_pre,
    const float* __restrict__ a_post, const float* __restrict__ a_res,
    const float* __restrict__ sw_norm, const int* __restrict__ list,
    const int* __restrict__ counts, const int* __restrict__ offs,
    __hip_bfloat16* __restrict__ hA, float* __restrict__ Hpost,
    float* __restrict__ Hres)
{
    int k = blockIdx.y;
    int i = blockIdx.x;
    if (i >= counts[k]) return;
    int bt = list[k * BT_TOT + i];
    int e = k + 1;
    int b = bt >> 10, t = bt & 1023;
    int tid = threadIdx.x;
    __shared__ float HpreS[4];
    if (tid == 0) {
        const float* s = Cproj + (size_t)bt * PHI_ROWS_P + k * 24;
        float ap = a_pre[e], aq = a_post[e], ar = a_res[e];
#pragma unroll
        for (int n = 0; n < 4; ++n)
            HpreS[n] = sigmoidf_(ap * s[n] + b_pre[e * 4 + n]);
#pragma unroll
        for (int n = 0; n < 4; ++n)
            Hpost[((size_t)k * BT_TOT + bt) * 4 + n] =
                2.f * sigmoidf_(aq * s[4 + n] + b_post[e * 4 + n]);
        float M[16];
#pragma unroll
        for (int j = 0; j < 16; ++j) M[j] = expf(ar * s[8 + j] + b_res[e * 16 + j]);
#pragma unroll
        for (int it = 0; it < 6; ++it) {
#pragma unroll
            for (int r = 0; r < 4; ++r) {
                float iv = 1.f / (M[r*4] + M[r*4+1] + M[r*4+2] + M[r*4+3]);
                M[r*4] *= iv; M[r*4+1] *= iv; M[r*4+2] *= iv; M[r*4+3] *= iv;
            }
#pragma unroll
            for (int c = 0; c < 4; ++c) {
                float iv = 1.f / (M[c] + M[4+c] + M[8+c] + M[12+c]);
                M[c] *= iv; M[4+c] *= iv; M[8+c] *= iv; M[12+c] *= iv;
            }
        }
#pragma unroll
        for (int j = 0; j < 16; ++j) Hres[((size_t)k * BT_TOT + bt) * 16 + j] = M[j];
    }
    __syncthreads();
    float hp[4];
#pragma unroll
    for (int n = 0; n < 4; ++n) hp[n] = HpreS[n];
    float he[2]; float ss = 0.f;
#pragma unroll
    for (int w = 0; w < 2; ++w) {
        int d = tid + w * 256;
        float v = 0.f;
#pragma unroll
        for (int n = 0; n < 4; ++n)
            v += hp[n] * stream[(((size_t)b * 4 + n) * T_LEN + t) * D_H + d];
        he[w] = v; ss += v * v;
    }
#pragma unroll
    for (int off = 32; off; off >>= 1) ss += __shfl_down(ss, off, 64);
    __shared__ float red[4];
    int wave = tid >> 6, lane = tid & 63;
    if (lane == 0) red[wave] = ss;
    __syncthreads();
    float tot = red[0] + red[1] + red[2] + red[3];
    float r = rsqrtf(tot / (float)D_H + 1e-8f);
    size_t row = (size_t)(offs[k] + i);
#pragma unroll
    for (int w = 0; w < 2; ++w) {
        int d = tid + w * 256;
        hA[row * D_H + d] = __float2bfloat16(he[w] * r * sw_norm[(size_t)e * D_H + d]);
    }
}

// ---------------- combine: out = sum_k gate*(H_res@stream + H_post*oute) ----------------
__global__ __launch_bounds__(256) void combine_kernel(
    const float* __restrict__ stream, const __hip_bfloat16* __restrict__ outeA,
    const float* __restrict__ Hpost, const float* __restrict__ Hres,
    const float* __restrict__ gate_all, const int* __restrict__ pos,
    const int* __restrict__ offs, float* __restrict__ out)
{
    int bt = blockIdx.x; int b = bt >> 10; int t = bt & 1023;
    int tid = threadIdx.x;
    float s[2][4], accv[2][4];
#pragma unroll
    for (int w = 0; w < 2; ++w) {
        int d = tid + w * 256;
#pragma unroll
        for (int n = 0; n < 4; ++n) {
            s[w][n] = stream[(((size_t)b * 4 + n) * T_LEN + t) * D_H + d];
            accv[w][n] = 0.f;
        }
    }
    for (int k = 0; k < KEXP; ++k) {
        float gate = gate_all[(size_t)bt * 16 + k + 1];
        if (gate == 0.f) continue;
        size_t row = (size_t)(offs[k] + pos[k * BT_TOT + bt]);
        float hr[16], hp[4];
#pragma unroll
        for (int i = 0; i < 16; ++i) hr[i] = Hres[((size_t)k * BT_TOT + bt) * 16 + i];
#pragma unroll
        for (int i = 0; i < 4; ++i) hp[i] = Hpost[((size_t)k * BT_TOT + bt) * 4 + i];
#pragma unroll
        for (int w = 0; w < 2; ++w) {
            int d = tid + w * 256;
            float oe = __bfloat162float(outeA[row * D_H + d]);
#pragma unroll
            for (int i = 0; i < 4; ++i) {
                float v = hp[i] * oe + hr[i*4+0]*s[w][0] + hr[i*4+1]*s[w][1]
                        + hr[i*4+2]*s[w][2] + hr[i*4+3]*s[w][3];
                accv[w][i] += gate * v;
            }
        }
    }
#pragma unroll
    for (int w = 0; w < 2; ++w) {
        int d = tid + w * 256;
#pragma unroll
        for (int i = 0; i < 4; ++i)
            out[(((size_t)b * 4 + i) * T_LEN + t) * D_H + d] = accv[w][i];
    }
}

extern "C" void kernel_launch(void* const* d_in, const int* in_sizes, int n_in,
                              void* d_out, int out_size, void* d_ws, size_t ws_size,
                              hipStream_t stream) {
    const float* stream_in = (const float*)d_in[0];
    const float* norm_w    = (const float*)d_in[1];
    const float* phi_pre   = (const float*)d_in[2];
    const float* phi_post  = (const float*)d_in[3];
    const float* phi_res   = (const float*)d_in[4];
    const float* b_pre     = (const float*)d_in[5];
    const float* b_post    = (const float*)d_in[6];
    const float* b_res     = (const float*)d_in[7];
    const float* alpha_pre = (const float*)d_in[8];
    const float* alpha_post= (const float*)d_in[9];
    const float* alpha_res = (const float*)d_in[10];
    const float* sw_norm   = (const float*)d_in[11];
    const float* wd_w      = (const float*)d_in[12];
    const float* wu_w      = (const float*)d_in[13];
    const float* gate_w    = (const float*)d_in[14];
    const float* up_w      = (const float*)d_in[15];
    const float* down_w    = (const float*)d_in[16];
    const float* router_w  = (const float*)d_in[17];

    float* out = (float*)d_out;
    const int SU_N = 2 * 4 * T_LEN * D_H;
    float* gate_out = out + SU_N;
    float* lp_out = gate_out + BT_TOT * 16;

    // ---- workspace carve-up ----
    char* p = (char*)d_ws;
    __hip_bfloat16* xn     = (__hip_bfloat16*)p; p += (size_t)BT_TOT * ND * 2;
    __hip_bfloat16* phiall = (__hip_bfloat16*)p; p += (size_t)PHI_ROWS_P * ND * 2;
    float* Cproj = (float*)p; p += (size_t)BT_TOT * PHI_ROWS_P * 4;
    float* Hpost = (float*)p; p += (size_t)KEXP * BT_TOT * 4 * 4;
    float* Hres  = (float*)p; p += (size_t)KEXP * BT_TOT * 16 * 4;
    int* cnt  = (int*)p; p += 256;
    int* offs = (int*)p; p += 256;
    int* list = (int*)p; p += (size_t)KEXP * BT_TOT * 4;
    int* pos  = (int*)p; p += (size_t)KEXP * BT_TOT * 4;
    __hip_bfloat16* hA    = (__hip_bfloat16*)p; p += (size_t)PAIR_CAP * D_H * 2;
    __hip_bfloat16* s1A   = (__hip_bfloat16*)p; p += (size_t)PAIR_CAP * D_H * 2;
    __hip_bfloat16* outeA = (__hip_bfloat16*)p; p += (size_t)PAIR_CAP * D_H * 2;
    __hip_bfloat16* tA    = (__hip_bfloat16*)p; p += (size_t)PAIR_CAP * DFFN_P * 2;
    size_t fixed_bytes = (size_t)(p - (char*)d_ws);
    size_t perW = (size_t)EXPW * 2;
    size_t avail = ws_size > fixed_bytes ? ws_size - fixed_bytes : 0;
    int G = (int)(avail / perW);
    if (G > KEXP) G = KEXP;
    if (G < 1) G = 1;
    __hip_bfloat16* wbuf = (__hip_bfloat16*)p;

    // ---- prologue ----
    hipMemsetAsync(cnt, 0, 64, stream);
    hipMemsetAsync(Cproj, 0, (size_t)BT_TOT * PHI_ROWS_P * 4, stream);
    router_kernel<<<BT_TOT, 64, 0, stream>>>(
        stream_in, router_w, gate_out, lp_out, cnt, list, pos);
    scan_kernel<<<1, 64, 0, stream>>>(cnt, offs);
    xn_kernel<<<BT_TOT, 256, 0, stream>>>(stream_in, xn);
    cvt_phi_kernel<<<(PHI_ROWS_P * ND) / 256, 256, 0, stream>>>(
        norm_w, phi_pre, phi_post, phi_res, phiall);
    // split-K=8: 384 blocks (was 192 -> 0.75 blocks/CU, latency-bound)
    gemm_dense<<<dim3(3, 16, 8), 256, 0, stream>>>(
        xn, phiall, Cproj, ND, PHI_ROWS_P, 256, 256);
    h_kernel<<<dim3(BT_TOT, KEXP), 256, 0, stream>>>(
        stream_in, Cproj, b_pre, b_post, b_res, alpha_pre, alpha_post, alpha_res,
        sw_norm, list, cnt, offs, hA, Hpost, Hres);

    // ---- expert weight groups ----
    for (int kg = 0; kg < KEXP; kg += G) {
        int Gc = (kg + G <= KEXP) ? G : (KEXP - kg);
        int e0 = kg + 1;
        cvt_all_kernel<<<dim3(448, 5, Gc), 256, 0, stream>>>(
            wd_w, wu_w, gate_w, up_w, down_w, wbuf, e0);
        // s1 = silu(h@wd^T)  ||  t = silu(h@gate^T)*(h@up^T)
        gemm_stage1<<<dim3(11, 16, Gc), 512, 0, stream>>>(
            hA, wbuf, s1A, tA, cnt, offs, kg);
        // oute = sigmoid(s1@wu^T) * (t@down^T)
        gemm_final<<<dim3(4, 16, Gc), 512, 0, stream>>>(
            s1A, tA, wbuf, outeA, cnt, offs, kg);
    }

    combine_kernel<<<BT_TOT, 256, 0, stream>>>(
        stream_in, outeA, Hpost, Hres, gate_out, pos, offs, out);
}